// Round 5
// baseline (1233.063 us; speedup 1.0000x reference)
//
#include <hip/hip_runtime.h>
#include <hip/hip_bf16.h>
#include <math.h>

typedef __bf16    bf16x8 __attribute__((ext_vector_type(8)));
typedef _Float16  f16x8  __attribute__((ext_vector_type(8)));
typedef float     f32x4  __attribute__((ext_vector_type(4)));

#define MFMA16(a, b, c) __builtin_amdgcn_mfma_f32_16x16x32_bf16((a), (b), (c), 0, 0, 0)
#define MFMAH(a, b, c)  __builtin_amdgcn_mfma_f32_16x16x32_f16((a), (b), (c), 0, 0, 0)

static constexpr int    kB  = 16;
static constexpr int    kS  = 2048;
static constexpr int    kC  = 512;
static constexpr size_t kNE = (size_t)kB * kS * kC;  // 16777216

static __device__ __forceinline__ void split_bf16(float v, __bf16 &hi, __bf16 &lo) {
  hi = (__bf16)v;
  lo = (__bf16)(v - (float)hi);
}

// Byte offset into a [rows][64] bf16 tile (128 B rows), XOR-swizzled in 16 B chunks.
static __device__ __forceinline__ int swzb(int row, int e) {
  return ((row << 7) + (e << 1)) ^ ((row & 7) << 4);
}

static __device__ __forceinline__ void split_store16_swz(
    float4 v0, float4 v1, float4 v2, float4 v3, char* hi, char* lo, int row, int e0) {
  float vv[16] = {v0.x, v0.y, v0.z, v0.w, v1.x, v1.y, v1.z, v1.w,
                  v2.x, v2.y, v2.z, v2.w, v3.x, v3.y, v3.z, v3.w};
  bf16x8 h0, h1, l0, l1;
#pragma unroll
  for (int i = 0; i < 8; ++i) {
    __bf16 a, b;
    split_bf16(vv[i], a, b);     h0[i] = a; l0[i] = b;
    split_bf16(vv[8 + i], a, b); h1[i] = a; l1[i] = b;
  }
  *(bf16x8*)(hi + swzb(row, e0))     = h0;
  *(bf16x8*)(hi + swzb(row, e0 + 8)) = h1;
  *(bf16x8*)(lo + swzb(row, e0))     = l0;
  *(bf16x8*)(lo + swzb(row, e0 + 8)) = l1;
}

// ---------------- K1a: t = tanh(x') in fp16 (single; |t|<=1, rel err 2^-12) ----------------
__global__ __launch_bounds__(256) void k_tanh_f16(
    const float* __restrict__ xp, _Float16* __restrict__ th) {
  size_t i = ((size_t)blockIdx.x * 256 + threadIdx.x) * 8;
  float4 a = *(const float4*)(xp + i);
  float4 b = *(const float4*)(xp + i + 4);
  float v[8] = {a.x, a.y, a.z, a.w, b.x, b.y, b.z, b.w};
  f16x8 h;
#pragma unroll
  for (int k = 0; k < 8; ++k) h[k] = (_Float16)tanhf(v[k]);
  *(f16x8*)(th + i) = h;
}

// ---------------- K1c: x (fp32 [b][t][c]) -> fp16 transposed [b][c][t] ----------------
__global__ __launch_bounds__(256) void k_transpose_x(
    const float* __restrict__ x, _Float16* __restrict__ xbt) {
  __shared__ float tile[64][65];
  int bid = blockIdx.x;              // 16 * 32 * 8 = 4096
  int b   = bid >> 8;
  int t0  = ((bid >> 3) & 31) * 64;
  int c0  = (bid & 7) * 64;
  int row = threadIdx.x >> 2;
  int seg = threadIdx.x & 3;
  const float* src = x + (size_t)(b * kS + t0 + row) * kC + c0 + seg * 16;
  float4 v0 = *(const float4*)(src + 0);
  float4 v1 = *(const float4*)(src + 4);
  float4 v2 = *(const float4*)(src + 8);
  float4 v3 = *(const float4*)(src + 12);
  float vv[16] = {v0.x, v0.y, v0.z, v0.w, v1.x, v1.y, v1.z, v1.w,
                  v2.x, v2.y, v2.z, v2.w, v3.x, v3.y, v3.z, v3.w};
#pragma unroll
  for (int i = 0; i < 16; ++i) tile[row][seg * 16 + i] = vv[i];
  __syncthreads();
  f16x8 o0, o1;
#pragma unroll
  for (int i = 0; i < 8; ++i) o0[i] = (_Float16)tile[seg * 16 + i][row];
#pragma unroll
  for (int i = 0; i < 8; ++i) o1[i] = (_Float16)tile[seg * 16 + 8 + i][row];
  _Float16* dst = xbt + (size_t)(b * kC + c0 + row) * kS + t0 + seg * 16;
  *(f16x8*)(dst)     = o0;
  *(f16x8*)(dst + 8) = o1;
}

// ---------------- K1b: q = x' @ W^T + bias (fp32-accurate), emit fp16 hi/lo ----------------
__global__ __launch_bounds__(256) void k_qgemm(
    const float* __restrict__ xp, const float* __restrict__ W,
    const float* __restrict__ bias, _Float16* __restrict__ qh, _Float16* __restrict__ ql) {
  __shared__ __align__(16) char lds[32768];
  char* Ah = lds;
  char* Al = lds + 8192;
  char* Bh = lds + 16384;
  char* Bl = lds + 24576;

  int bid = blockIdx.x;
  int n0  = (bid & 7) * 64;
  int m0  = (bid >> 3) * 64;

  int tid  = threadIdx.x;
  int lane = tid & 63;
  int wave = tid >> 6;
  int qd   = lane >> 4;
  int cl   = lane & 15;
  int row  = tid >> 2;
  int seg  = tid & 3;

  f32x4 acc[4] = {};
  const float* srcA = xp + (size_t)(m0 + row) * kC + seg * 16;
  const float* srcB = W  + (size_t)(n0 + row) * kC + seg * 16;

  float4 va0, va1, va2, va3, vb0, vb1, vb2, vb3;
  auto load_ab = [&](int kc) {
    const float* a = srcA + kc * 64;
    va0 = *(const float4*)(a);      va1 = *(const float4*)(a + 4);
    va2 = *(const float4*)(a + 8);  va3 = *(const float4*)(a + 12);
    const float* bb = srcB + kc * 64;
    vb0 = *(const float4*)(bb);     vb1 = *(const float4*)(bb + 4);
    vb2 = *(const float4*)(bb + 8); vb3 = *(const float4*)(bb + 12);
  };

  load_ab(0);
  for (int kc = 0; kc < 8; ++kc) {
    split_store16_swz(va0, va1, va2, va3, Ah, Al, row, seg * 16);
    split_store16_swz(vb0, vb1, vb2, vb3, Bh, Bl, row, seg * 16);
    __syncthreads();
    if (kc < 7) load_ab(kc + 1);
    __builtin_amdgcn_s_setprio(1);
#pragma unroll
    for (int ks = 0; ks < 2; ++ks) {
      int ka = ks * 32 + qd * 8;
      bf16x8 ah = *(const bf16x8*)(Ah + swzb(wave * 16 + cl, ka));
      bf16x8 al = *(const bf16x8*)(Al + swzb(wave * 16 + cl, ka));
#pragma unroll
      for (int j = 0; j < 4; ++j) {
        bf16x8 bh = *(const bf16x8*)(Bh + swzb(j * 16 + cl, ka));
        bf16x8 bl = *(const bf16x8*)(Bl + swzb(j * 16 + cl, ka));
        acc[j] = MFMA16(ah, bh, acc[j]);
        acc[j] = MFMA16(ah, bl, acc[j]);
        acc[j] = MFMA16(al, bh, acc[j]);
      }
    }
    __builtin_amdgcn_s_setprio(0);
    __syncthreads();
  }
#pragma unroll
  for (int j = 0; j < 4; ++j) {
    int d = n0 + j * 16 + cl;
    float bv = bias[d];
#pragma unroll
    for (int r = 0; r < 4; ++r) {
      int m = m0 + wave * 16 + qd * 4 + r;
      float v = acc[j][r] + bv;
      _Float16 h = (_Float16)v;
      _Float16 l = (_Float16)(v - (float)h);
      qh[(size_t)m * kC + d] = h;
      ql[(size_t)m * kC + d] = l;
    }
  }
}

// ---------------- K2: fused flash attention, 64-row blocks, 256 thr, fp16 ----------------
// Per-wave register blocking is the point: each wave owns ALL 64 s-rows.
// Score: M_t=4 x N_t=2 (wave = 64 rows x 32 cols), 8 LDS reads / 16 MFMAs.
// PV:    M_t=4 x N_t=8 (wave = 64 rows x 128 cols), 12 reads / 32 MFMAs.
// T single fp16 + q hi/lo fp16 -> 2-MFMA score (fp32-grade logits).
// Cross-wave row max/sum via tiny [64][4] f32 stat arrays (rows split over 4 waves).
// LDS 58 KB -> 2 independent blocks/CU (cross-block latency hiding).
__global__ __launch_bounds__(256, 2) void k_attn(
    const _Float16* __restrict__ th, const _Float16* __restrict__ qh,
    const _Float16* __restrict__ ql, const _Float16* __restrict__ xbt,
    float* __restrict__ out) {
  __shared__ __align__(16) char lds[59392];
  char*  Ta    = lds;                    // [64][64]  f16  8K  (score)
  char*  Qh    = lds + 8192;             // [128][64] f16 16K  (score)
  char*  Ql    = lds + 24576;            // [128][64] f16 16K  (score)
  char*  Xt    = lds;                    // [512][32] f16 32K  (PV; aliases score bufs)
  char*  P     = lds + 40960;            // [64][128] f16 16K  (dedicated)
  float* statm = (float*)(lds + 57344);  // [64][4]
  float* stats = (float*)(lds + 58368);  // [64][4]

  int bid = blockIdx.x;                  // 512
  int swz = (bid & 7) * 64 + (bid >> 3); // XCD r holds 64 consecutive swz -> 2 batches/XCD
  int b   = swz >> 5;
  int s0  = (swz & 31) * 64;

  int tid  = threadIdx.x;
  int lane = tid & 63;
  int wv   = tid >> 6;                   // 0..3
  int qd   = lane >> 4;
  int cl   = lane & 15;

  const float LOG2E = 1.4426950408889634f;

  float m_r[16], l_r[16];                // [mt*4+r]: row = mt*16 + qd*4 + r
#pragma unroll
  for (int i = 0; i < 16; ++i) { m_r[i] = -INFINITY; l_r[i] = 0.f; }
  f32x4 O[4][8] = {};                    // rows mt*16+qd*4+r, cols wv*128+nt*16+cl

  auto stage_score = [&](int kc, int t0) {
    { // Ta: 64 rows x 64 k, fp16 single
      int ar = tid >> 2, as = tid & 3;
      const _Float16* ga = th + (size_t)(b * kS + s0 + ar) * kC + kc * 64 + as * 16;
      f16x8 a0 = *(const f16x8*)ga;
      f16x8 a1 = *(const f16x8*)(ga + 8);
      *(f16x8*)(Ta + ar * 128 + (((as * 2)     ^ (ar & 7)) << 4)) = a0;
      *(f16x8*)(Ta + ar * 128 + (((as * 2 + 1) ^ (ar & 7)) << 4)) = a1;
    }
    { // Qh/Ql: 128 rows x 64 k
      int qr = tid >> 1, qs = tid & 1;
      size_t gq = (size_t)(b * kS + t0 + qr) * kC + kc * 64 + qs * 32;
#pragma unroll
      for (int u = 0; u < 4; ++u) {
        f16x8 vh = *(const f16x8*)(qh + gq + u * 8);
        f16x8 vl = *(const f16x8*)(ql + gq + u * 8);
        int cc = (((qs * 4 + u) ^ (qr & 7)) << 4);
        *(f16x8*)(Qh + qr * 128 + cc) = vh;
        *(f16x8*)(Ql + qr * 128 + cc) = vl;
      }
    }
  };
  auto stage_x = [&](int sub, int t0) {  // Xt[512 c][32 t], 64 B rows, 2-bit folded swizzle
#pragma unroll
    for (int u = 0; u < 2; ++u) {
      int r = tid * 2 + u;
      const _Float16* gx = xbt + (size_t)(b * kC + r) * kS + t0 + sub * 32;
#pragma unroll
      for (int j = 0; j < 4; ++j) {
        f16x8 v = *(const f16x8*)(gx + j * 8);
        int cc = ((j ^ (r & 3) ^ ((r >> 2) & 3)) << 4);
        *(f16x8*)(Xt + r * 64 + cc) = v;
      }
    }
  };

  for (int tt = 0; tt < 16; ++tt) {
    int t0 = tt * 128;
    f32x4 S[4][2] = {};
    // ----- score: S[64 x 128] = T . Q^T over K=512 (f16, 2-MFMA hi/lo) -----
    for (int kc = 0; kc < 8; ++kc) {
      stage_score(kc, t0);
      __syncthreads();
      __builtin_amdgcn_s_setprio(1);
#pragma unroll
      for (int ks = 0; ks < 2; ++ks) {
        f16x8 ta[4], qbh[2], qbl[2];
#pragma unroll
        for (int mt = 0; mt < 4; ++mt) {
          int rr = mt * 16 + cl;
          ta[mt] = *(const f16x8*)(Ta + rr * 128 + ((((ks * 4 + qd) ^ (rr & 7))) << 4));
        }
#pragma unroll
        for (int nt = 0; nt < 2; ++nt) {
          int rr = wv * 32 + nt * 16 + cl;
          int cc = ((((ks * 4 + qd) ^ (rr & 7))) << 4);
          qbh[nt] = *(const f16x8*)(Qh + rr * 128 + cc);
          qbl[nt] = *(const f16x8*)(Ql + rr * 128 + cc);
        }
#pragma unroll
        for (int mt = 0; mt < 4; ++mt)
#pragma unroll
          for (int nt = 0; nt < 2; ++nt) {
            S[mt][nt] = MFMAH(ta[mt], qbh[nt], S[mt][nt]);
            S[mt][nt] = MFMAH(ta[mt], qbl[nt], S[mt][nt]);
          }
      }
      __builtin_amdgcn_s_setprio(0);
      __syncthreads();
    }
    // ----- online softmax: rows split over lanes (qd,r); cols split over waves -----
    float rm[16];
#pragma unroll
    for (int mt = 0; mt < 4; ++mt)
#pragma unroll
      for (int r = 0; r < 4; ++r)
        rm[mt * 4 + r] = fmaxf(S[mt][0][r], S[mt][1][r]);
#pragma unroll
    for (int mk = 1; mk < 16; mk <<= 1)
#pragma unroll
      for (int i = 0; i < 16; ++i) rm[i] = fmaxf(rm[i], __shfl_xor(rm[i], mk, 64));
    if (cl == 0) {
#pragma unroll
      for (int mt = 0; mt < 4; ++mt)
#pragma unroll
        for (int r = 0; r < 4; ++r)
          statm[(mt * 16 + qd * 4 + r) * 4 + wv] = rm[mt * 4 + r];
    }
    __syncthreads();                     // B1: max partials visible
    float alpha[16];
#pragma unroll
    for (int mt = 0; mt < 4; ++mt)
#pragma unroll
      for (int r = 0; r < 4; ++r) {
        int i = mt * 4 + r;
        f32x4 pm = *(const f32x4*)&statm[(mt * 16 + qd * 4 + r) * 4];
        float M = fmaxf(fmaxf(fmaxf(pm[0], pm[1]), fmaxf(pm[2], pm[3])), m_r[i]);
        alpha[i] = exp2f((m_r[i] - M) * LOG2E);
        m_r[i] = M;
      }
    float rs[16];
#pragma unroll
    for (int mt = 0; mt < 4; ++mt)
#pragma unroll
      for (int r = 0; r < 4; ++r) {
        int i = mt * 4 + r;
        float p0 = exp2f((S[mt][0][r] - m_r[i]) * LOG2E);
        float p1 = exp2f((S[mt][1][r] - m_r[i]) * LOG2E);
        S[mt][0][r] = p0; S[mt][1][r] = p1;
        rs[i] = p0 + p1;
      }
#pragma unroll
    for (int mk = 1; mk < 16; mk <<= 1)
#pragma unroll
      for (int i = 0; i < 16; ++i) rs[i] += __shfl_xor(rs[i], mk, 64);
    if (cl == 0) {
#pragma unroll
      for (int mt = 0; mt < 4; ++mt)
#pragma unroll
        for (int r = 0; r < 4; ++r)
          stats[(mt * 16 + qd * 4 + r) * 4 + wv] = rs[mt * 4 + r];
    }
    // write P (C-layout -> A-layout) and rescale O
#pragma unroll
    for (int mt = 0; mt < 4; ++mt)
#pragma unroll
      for (int nt = 0; nt < 2; ++nt)
#pragma unroll
        for (int r = 0; r < 4; ++r) {
          int row = mt * 16 + qd * 4 + r;
          int col = wv * 32 + nt * 16 + cl;
          int off = row * 256 + ((((col >> 3) ^ (row & 7)) << 4)) + ((col & 7) << 1);
          *(_Float16*)(P + off) = (_Float16)S[mt][nt][r];
        }
#pragma unroll
    for (int mt = 0; mt < 4; ++mt)
#pragma unroll
      for (int nt = 0; nt < 8; ++nt)
#pragma unroll
        for (int r = 0; r < 4; ++r)
          O[mt][nt][r] *= alpha[mt * 4 + r];
    __syncthreads();                     // B2: sum partials + P visible
#pragma unroll
    for (int mt = 0; mt < 4; ++mt)
#pragma unroll
      for (int r = 0; r < 4; ++r) {
        int i = mt * 4 + r;
        f32x4 ps = *(const f32x4*)&stats[(mt * 16 + qd * 4 + r) * 4];
        l_r[i] = l_r[i] * alpha[i] + (ps[0] + ps[1] + ps[2] + ps[3]);
      }
    // ----- PV: O[64 x 512] += P[64 x 128] . Xbt[128 x 512] -----
#pragma unroll
    for (int sub = 0; sub < 4; ++sub) {
      stage_x(sub, t0);
      __syncthreads();
      f16x8 pa[4];
#pragma unroll
      for (int mt = 0; mt < 4; ++mt) {
        int row = mt * 16 + cl;
        pa[mt] = *(const f16x8*)(P + row * 256 + ((((sub * 4 + qd) ^ (row & 7))) << 4));
      }
      __builtin_amdgcn_s_setprio(1);
#pragma unroll
      for (int nt = 0; nt < 8; ++nt) {
        int xr = wv * 128 + nt * 16 + cl;
        f16x8 xb = *(const f16x8*)(Xt + xr * 64 + ((qd ^ (xr & 3) ^ ((xr >> 2) & 3)) << 4));
#pragma unroll
        for (int mt = 0; mt < 4; ++mt)
          O[mt][nt] = MFMAH(pa[mt], xb, O[mt][nt]);
      }
      __builtin_amdgcn_s_setprio(0);
      __syncthreads();
    }
  }
  // ----- epilogue: out = tanh(O / l) -----
#pragma unroll
  for (int mt = 0; mt < 4; ++mt)
#pragma unroll
    for (int r = 0; r < 4; ++r) {
      float inv = __builtin_amdgcn_rcpf(l_r[mt * 4 + r]);   // l >= 1
      size_t ro = (size_t)(b * kS + s0 + mt * 16 + qd * 4 + r) * kC + wv * 128;
#pragma unroll
      for (int nt = 0; nt < 8; ++nt) {
        float v = O[mt][nt][r] * inv;
        float e = exp2f(2.f * LOG2E * v);
        out[ro + nt * 16 + cl] = 1.f - 2.f * __builtin_amdgcn_rcpf(e + 1.f);
      }
    }
}

extern "C" void kernel_launch(void* const* d_in, const int* in_sizes, int n_in,
                              void* d_out, int out_size, void* d_ws, size_t ws_size,
                              hipStream_t stream) {
  const float* x    = (const float*)d_in[0];
  const float* xp   = (const float*)d_in[1];
  const float* W    = (const float*)d_in[2];
  const float* bias = (const float*)d_in[3];
  float* out = (float*)d_out;

  // workspace (fp16): th | q_hi | q_lo | x_bt  -> 4 * 16.78M * 2B = 128 MiB
  _Float16* ws  = (_Float16*)d_ws;
  _Float16* th  = ws;
  _Float16* qh  = ws + kNE;
  _Float16* ql  = ws + 2 * kNE;
  _Float16* xbt = ws + 3 * kNE;

  k_tanh_f16<<<8192, 256, 0, stream>>>(xp, th);
  k_transpose_x<<<4096, 256, 0, stream>>>(x, xbt);
  k_qgemm<<<4096, 256, 0, stream>>>(xp, W, bias, qh, ql);
  k_attn<<<512, 256, 0, stream>>>(th, qh, ql, xbt, out);
}

// Round 6
// 900.387 us; speedup vs baseline: 1.3695x; 1.3695x over previous
//
#include <hip/hip_runtime.h>
#include <hip/hip_bf16.h>
#include <math.h>

typedef __bf16 bf16x8 __attribute__((ext_vector_type(8)));
typedef float  f32x4  __attribute__((ext_vector_type(4)));

#define MFMA16(a, b, c) __builtin_amdgcn_mfma_f32_16x16x32_bf16((a), (b), (c), 0, 0, 0)

static constexpr int    kB  = 16;
static constexpr int    kS  = 2048;
static constexpr int    kC  = 512;
static constexpr size_t kNE = (size_t)kB * kS * kC;  // 16777216

static __device__ __forceinline__ void split_bf16(float v, __bf16 &hi, __bf16 &lo) {
  hi = (__bf16)v;                 // RNE
  lo = (__bf16)(v - (float)hi);   // residual, ~2^-17 combined rel error
}

// global -> LDS direct DMA, 16B per lane. LDS dest = wave-uniform base + lane*16.
static __device__ __forceinline__ void gload16(const void* g, void* l) {
  __builtin_amdgcn_global_load_lds(
      (const __attribute__((address_space(1))) char*)g,
      (__attribute__((address_space(3))) char*)l, 16, 0, 0);
}

// ---------------- K1a: t = tanh(x'), split to bf16 hi/lo ----------------
__global__ __launch_bounds__(256) void k_tanh_split(
    const float* __restrict__ xp, __bf16* __restrict__ th, __bf16* __restrict__ tl) {
  size_t i = ((size_t)blockIdx.x * 256 + threadIdx.x) * 8;
  float4 a = *(const float4*)(xp + i);
  float4 b = *(const float4*)(xp + i + 4);
  float v[8] = {a.x, a.y, a.z, a.w, b.x, b.y, b.z, b.w};
  bf16x8 h, l;
#pragma unroll
  for (int k = 0; k < 8; ++k) {
    float t = tanhf(v[k]);
    __bf16 hh, ll;
    split_bf16(t, hh, ll);
    h[k] = hh; l[k] = ll;
  }
  *(bf16x8*)(th + i) = h;
  *(bf16x8*)(tl + i) = l;
}

// ---------------- K1c: x (fp32 [b][t][c]) -> bf16 transposed [b][c][t] ----------------
__global__ __launch_bounds__(256) void k_transpose_x(
    const float* __restrict__ x, __bf16* __restrict__ xbt) {
  __shared__ float tile[64][65];
  int bid = blockIdx.x;              // 16 * 32 * 8 = 4096
  int b   = bid >> 8;
  int t0  = ((bid >> 3) & 31) * 64;
  int c0  = (bid & 7) * 64;
  int row = threadIdx.x >> 2;        // 0..63
  int seg = threadIdx.x & 3;         // 0..3 (16 elems each)
  const float* src = x + (size_t)(b * kS + t0 + row) * kC + c0 + seg * 16;
  float4 v0 = *(const float4*)(src + 0);
  float4 v1 = *(const float4*)(src + 4);
  float4 v2 = *(const float4*)(src + 8);
  float4 v3 = *(const float4*)(src + 12);
  float vv[16] = {v0.x, v0.y, v0.z, v0.w, v1.x, v1.y, v1.z, v1.w,
                  v2.x, v2.y, v2.z, v2.w, v3.x, v3.y, v3.z, v3.w};
#pragma unroll
  for (int i = 0; i < 16; ++i) tile[row][seg * 16 + i] = vv[i];
  __syncthreads();
  bf16x8 o0, o1;
#pragma unroll
  for (int i = 0; i < 8; ++i) o0[i] = (__bf16)tile[seg * 16 + i][row];
#pragma unroll
  for (int i = 0; i < 8; ++i) o1[i] = (__bf16)tile[seg * 16 + 8 + i][row];
  __bf16* dst = xbt + (size_t)(b * kC + c0 + row) * kS + t0 + seg * 16;
  *(bf16x8*)(dst)     = o0;
  *(bf16x8*)(dst + 8) = o1;
}

// ---------------- K1b: q = x' @ W^T + bias, fp32-accurate via split-bf16 3-MFMA ----------------
__global__ __launch_bounds__(256) void k_qgemm(
    const float* __restrict__ xp, const float* __restrict__ W,
    const float* __restrict__ bias, __bf16* __restrict__ qh, __bf16* __restrict__ ql) {
  __shared__ __align__(16) __bf16 lds[4 * 4608];
  __bf16* Ah = lds;             // [64][72]
  __bf16* Al = lds + 4608;
  __bf16* Bh = lds + 9216;      // [64][72]
  __bf16* Bl = lds + 13824;

  int bid = blockIdx.x;         // 512 m-tiles * 8 n-tiles
  int n0  = (bid & 7) * 64;
  int m0  = (bid >> 3) * 64;

  int tid  = threadIdx.x;
  int lane = tid & 63;
  int wave = tid >> 6;
  int qd   = lane >> 4;
  int cl   = lane & 15;
  int row  = tid >> 2;
  int seg  = tid & 3;

  f32x4 acc[4] = {};

  auto stage16 = [&](const float* src, __bf16* hi, __bf16* lo, int o) {
    float4 v0 = *(const float4*)(src + 0);
    float4 v1 = *(const float4*)(src + 4);
    float4 v2 = *(const float4*)(src + 8);
    float4 v3 = *(const float4*)(src + 12);
    float vv[16] = {v0.x, v0.y, v0.z, v0.w, v1.x, v1.y, v1.z, v1.w,
                    v2.x, v2.y, v2.z, v2.w, v3.x, v3.y, v3.z, v3.w};
    bf16x8 h0, h1, l0, l1;
#pragma unroll
    for (int i = 0; i < 8; ++i) {
      __bf16 a, b;
      split_bf16(vv[i], a, b);     h0[i] = a; l0[i] = b;
      split_bf16(vv[8 + i], a, b); h1[i] = a; l1[i] = b;
    }
    *(bf16x8*)&hi[o]     = h0;
    *(bf16x8*)&hi[o + 8] = h1;
    *(bf16x8*)&lo[o]     = l0;
    *(bf16x8*)&lo[o + 8] = l1;
  };

  for (int kc = 0; kc < 8; ++kc) {
    stage16(xp + (size_t)(m0 + row) * kC + kc * 64 + seg * 16, Ah, Al, row * 72 + seg * 16);
    stage16(W  + (size_t)(n0 + row) * kC + kc * 64 + seg * 16, Bh, Bl, row * 72 + seg * 16);
    __syncthreads();
    __builtin_amdgcn_s_setprio(1);
#pragma unroll
    for (int ks = 0; ks < 2; ++ks) {
      int ka = ks * 32 + qd * 8;
      bf16x8 ah = *(const bf16x8*)&Ah[(wave * 16 + cl) * 72 + ka];
      bf16x8 al = *(const bf16x8*)&Al[(wave * 16 + cl) * 72 + ka];
#pragma unroll
      for (int j = 0; j < 4; ++j) {
        bf16x8 bh = *(const bf16x8*)&Bh[(j * 16 + cl) * 72 + ka];
        bf16x8 bl = *(const bf16x8*)&Bl[(j * 16 + cl) * 72 + ka];
        acc[j] = MFMA16(ah, bh, acc[j]);
        acc[j] = MFMA16(ah, bl, acc[j]);
        acc[j] = MFMA16(al, bh, acc[j]);
      }
    }
    __builtin_amdgcn_s_setprio(0);
    __syncthreads();
  }
#pragma unroll
  for (int j = 0; j < 4; ++j) {
    int d = n0 + j * 16 + cl;
    float bv = bias[d];
#pragma unroll
    for (int r = 0; r < 4; ++r) {
      int m = m0 + wave * 16 + qd * 4 + r;
      float v = acc[j][r] + bv;
      __bf16 h, l;
      split_bf16(v, h, l);
      qh[(size_t)m * kC + d] = h;
      ql[(size_t)m * kC + d] = l;
    }
  }
}

// ---------------- K2: fused flash attention, 32-row blocks, occupancy-first ----------------
// R0's proven numerics/layouts; work decomposition cut in half so per-wave
// registers ~150 (acc 80) -> 3 waves/SIMD, 3 blocks/CU (12 waves vs R0's 8).
// Waves: rg = row group (16 rows), cg = col group (score 64 t-cols, PV 256 c-cols).
// B-tile staged via global_load_lds DMA (zero staging VGPRs, pre-swizzled source).
// LDS 44544 B: stats 512 | A(hi/lo) [32][72] pad | B(hi/lo) [128][64] swz-linear;
// P [32][136] aliases A; Xt0/Xt1 [64][136] alias B (all phase-disjoint).
__global__ __launch_bounds__(256, 3) void k_attn(
    const __bf16* __restrict__ th, const __bf16* __restrict__ tl,
    const __bf16* __restrict__ qh, const __bf16* __restrict__ ql,
    const __bf16* __restrict__ xbt, float* __restrict__ out) {
  __shared__ __align__(16) char lds[44544];
  float*  statm = (float*)lds;             // [2][32]
  float*  stats = (float*)(lds + 256);     // [2][32]
  __bf16* Ah    = (__bf16*)(lds + 512);    // [32][72]
  __bf16* Al    = (__bf16*)(lds + 5120);
  char*   Bh    = lds + 9728;              // [128][64] swz linear (DMA dest)
  char*   Bl    = lds + 26112;
  __bf16* P     = (__bf16*)(lds + 512);    // [32][136] alias A region
  __bf16* Xt0   = (__bf16*)(lds + 9728);   // [64][136] alias B region
  __bf16* Xt1   = (__bf16*)(lds + 27136);  // [64][136]

  int bid = blockIdx.x;                    // 1024
  int swz = (bid & 7) * 128 + (bid >> 3);  // 2 batches per XCD
  int b   = swz >> 6;
  int s0  = (swz & 63) * 32;

  int tid  = threadIdx.x;
  int lane = tid & 63;
  int wv   = tid >> 6;                     // 0..3
  int qd   = lane >> 4;
  int cl   = lane & 15;
  int rg   = wv & 1;                       // rows rg*16 .. +16
  int cg   = wv >> 1;                      // score cols cg*64; PV cols cg*256

  const float LOG2E = 1.4426950408889634f;

  float m_r[4], l_r[4];
#pragma unroll
  for (int r = 0; r < 4; ++r) { m_r[r] = -INFINITY; l_r[r] = 0.f; }
  f32x4 O[4][4] = {};   // O[step][nt]: rows rg*16+qd*4+r, col cg*256+step*64+nt*16+cl

  auto stage_score = [&](int kc, int t0q) {
    { // A: 32 rows x 64 k hi+lo, reg-staged into padded-72 (R0 layout)
      int ar = tid >> 3, as = tid & 7;
      size_t g = (size_t)(b * kS + s0 + ar) * kC + kc * 64 + as * 8;
      int o = ar * 72 + as * 8;
      *(bf16x8*)&Ah[o] = *(const bf16x8*)(th + g);
      *(bf16x8*)&Al[o] = *(const bf16x8*)(tl + g);
    }
    // B: 128 q-rows x 64 k via DMA, source pre-swizzled (slot r=s>>3, c=(s&7)^(r&7))
#pragma unroll
    for (int u = 0; u < 4; ++u) {
      int slot = wv * 256 + u * 64 + lane;
      int r = slot >> 3;
      int c = (slot & 7) ^ (r & 7);
      size_t g = (size_t)(b * kS + t0q + r) * kC + kc * 64 + c * 8;
      int ldoff = (wv * 256 + u * 64) * 16;   // wave-uniform; HW adds lane*16
      gload16(qh + g, Bh + ldoff);
      gload16(ql + g, Bl + ldoff);
    }
  };

  for (int tt = 0; tt < 16; ++tt) {
    int t0 = tt * 128;
    f32x4 Sacc[4] = {};
    // ----- score: S[32 x 128] = T . Q^T over K=512; wave = 16 rows x 64 cols -----
    for (int kc = 0; kc < 8; ++kc) {
      stage_score(kc, t0);
      __syncthreads();                     // drains DMA + A writes
      __builtin_amdgcn_s_setprio(1);
#pragma unroll
      for (int ks = 0; ks < 2; ++ks) {
        int ka = ks * 32 + qd * 8;
        bf16x8 ah = *(const bf16x8*)&Ah[(rg * 16 + cl) * 72 + ka];
        bf16x8 al = *(const bf16x8*)&Al[(rg * 16 + cl) * 72 + ka];
        int kchunk = ks * 4 + qd;
#pragma unroll
        for (int j = 0; j < 4; ++j) {
          int trow = cg * 64 + j * 16 + cl;
          int boff = trow * 128 + ((kchunk ^ (trow & 7)) << 4);
          bf16x8 bh = *(const bf16x8*)(Bh + boff);
          bf16x8 bl = *(const bf16x8*)(Bl + boff);
          Sacc[j] = MFMA16(ah, bh, Sacc[j]);
          Sacc[j] = MFMA16(ah, bl, Sacc[j]);
          Sacc[j] = MFMA16(al, bh, Sacc[j]);
        }
      }
      __builtin_amdgcn_s_setprio(0);
      __syncthreads();
    }
    // ----- online softmax; row = rg*16 + qd*4 + r; cols split across cg -----
    float rmax[4];
#pragma unroll
    for (int r = 0; r < 4; ++r) {
      float v = Sacc[0][r];
#pragma unroll
      for (int j = 1; j < 4; ++j) v = fmaxf(v, Sacc[j][r]);
      rmax[r] = v;
    }
#pragma unroll
    for (int mk = 1; mk < 16; mk <<= 1)
#pragma unroll
      for (int r = 0; r < 4; ++r)
        rmax[r] = fmaxf(rmax[r], __shfl_xor(rmax[r], mk, 64));
    if (cl == 0) {
#pragma unroll
      for (int r = 0; r < 4; ++r)
        statm[cg * 32 + rg * 16 + qd * 4 + r] = rmax[r];
    }
    __syncthreads();                       // B1: max partials visible
    float alpha[4], rsum[4];
#pragma unroll
    for (int r = 0; r < 4; ++r) {
      float om = statm[(cg ^ 1) * 32 + rg * 16 + qd * 4 + r];
      float M  = fmaxf(m_r[r], fmaxf(rmax[r], om));
      alpha[r] = exp2f((m_r[r] - M) * LOG2E);   // exp2(-inf)=0 on first tile
      m_r[r] = M;
      rsum[r] = 0.f;
    }
#pragma unroll
    for (int j = 0; j < 4; ++j)
#pragma unroll
      for (int r = 0; r < 4; ++r) {
        float p = exp2f((Sacc[j][r] - m_r[r]) * LOG2E);
        Sacc[j][r] = p;
        rsum[r] += p;
      }
#pragma unroll
    for (int mk = 1; mk < 16; mk <<= 1)
#pragma unroll
      for (int r = 0; r < 4; ++r)
        rsum[r] += __shfl_xor(rsum[r], mk, 64);
    if (cl == 0) {
#pragma unroll
      for (int r = 0; r < 4; ++r)
        stats[cg * 32 + rg * 16 + qd * 4 + r] = rsum[r];
    }
    // write P (C-layout -> A-layout); A region dead here
#pragma unroll
    for (int j = 0; j < 4; ++j)
#pragma unroll
      for (int r = 0; r < 4; ++r)
        P[(rg * 16 + qd * 4 + r) * 136 + cg * 64 + j * 16 + cl] = (__bf16)Sacc[j][r];
    // rescale O
    f32x4 av;
#pragma unroll
    for (int r = 0; r < 4; ++r) av[r] = alpha[r];
#pragma unroll
    for (int st = 0; st < 4; ++st)
#pragma unroll
      for (int nt = 0; nt < 4; ++nt)
        O[st][nt] *= av;
    __syncthreads();                       // B2: sum partials + P visible
#pragma unroll
    for (int r = 0; r < 4; ++r)
      l_r[r] = l_r[r] * alpha[r] + rsum[r] + stats[(cg ^ 1) * 32 + rg * 16 + qd * 4 + r];
    // ----- PV: O[32 x 512] += P[32 x 128] . Xbt[128 x 512]; wave = 16 rows x 256 cols -----
    bf16x8 pa[4];
#pragma unroll
    for (int ks = 0; ks < 4; ++ks)
      pa[ks] = *(const bf16x8*)&P[(rg * 16 + cl) * 136 + ks * 32 + qd * 8];
#pragma unroll
    for (int step = 0; step < 4; ++step) {
      { // stage channel chunks step (cg0) and step+4 (cg1); P untouched (B region)
        int xr = tid >> 2, xs = tid & 3;
        size_t g0 = ((size_t)b * kC + step * 64 + xr) * kS + t0 + xs * 32;
        size_t g1 = g0 + (size_t)256 * kS;
        int o = xr * 136 + xs * 32;
#pragma unroll
        for (int u = 0; u < 4; ++u)
          *(bf16x8*)&Xt0[o + u * 8] = *(const bf16x8*)(xbt + g0 + u * 8);
#pragma unroll
        for (int u = 0; u < 4; ++u)
          *(bf16x8*)&Xt1[o + u * 8] = *(const bf16x8*)(xbt + g1 + u * 8);
      }
      __syncthreads();
      const __bf16* Xt = cg ? Xt1 : Xt0;
      __builtin_amdgcn_s_setprio(1);
#pragma unroll
      for (int ks = 0; ks < 4; ++ks) {
        int ka = ks * 32 + qd * 8;
#pragma unroll
        for (int nt = 0; nt < 4; ++nt) {
          bf16x8 xb = *(const bf16x8*)&Xt[(nt * 16 + cl) * 136 + ka];
          O[step][nt] = MFMA16(pa[ks], xb, O[step][nt]);
        }
      }
      __builtin_amdgcn_s_setprio(0);
      __syncthreads();
    }
  }
  // ----- epilogue: out = tanh(O / l) -----
#pragma unroll
  for (int r = 0; r < 4; ++r) {
    float inv = __builtin_amdgcn_rcpf(l_r[r]);   // l >= 1 always
    size_t rowoff = (size_t)(b * kS + s0 + rg * 16 + qd * 4 + r) * kC + cg * 256;
#pragma unroll
    for (int st = 0; st < 4; ++st)
#pragma unroll
      for (int nt = 0; nt < 4; ++nt) {
        float v = O[st][nt][r] * inv;
        float e = exp2f(2.f * LOG2E * v);        // e^{2v}; |v| <= ~6
        out[rowoff + st * 64 + nt * 16 + cl] = 1.f - 2.f * __builtin_amdgcn_rcpf(e + 1.f);
      }
  }
}

extern "C" void kernel_launch(void* const* d_in, const int* in_sizes, int n_in,
                              void* d_out, int out_size, void* d_ws, size_t ws_size,
                              hipStream_t stream) {
  const float* x    = (const float*)d_in[0];
  const float* xp   = (const float*)d_in[1];
  const float* W    = (const float*)d_in[2];
  const float* bias = (const float*)d_in[3];
  float* out = (float*)d_out;

  // workspace layout (bf16): t_hi | t_lo | q_hi | q_lo | x_bt  -> 160 MiB
  __bf16* ws  = (__bf16*)d_ws;
  __bf16* th  = ws;
  __bf16* tl  = ws + kNE;
  __bf16* qh  = ws + 2 * kNE;
  __bf16* ql  = ws + 3 * kNE;
  __bf16* xbt = ws + 4 * kNE;

  k_tanh_split<<<8192, 256, 0, stream>>>(xp, th, tl);
  k_transpose_x<<<4096, 256, 0, stream>>>(x, xbt);
  k_qgemm<<<4096, 256, 0, stream>>>(xp, W, bias, qh, ql);
  k_attn<<<1024, 256, 0, stream>>>(th, tl, qh, ql, xbt, out);
}